// Round 4
// baseline (150.043 us; speedup 1.0000x reference)
//
#include <hip/hip_runtime.h>

// Problem constants (S == DIM == HID == 1024)
#define NH    8      // heads
#define NE    512    // experts per head-group (E)
#define NB    8      // batch
#define ND    1024   // DIM == HID == S
#define NROW  4096   // NB * NE  (rows of x)

typedef unsigned short u16;
typedef __attribute__((ext_vector_type(8))) short short8;
typedef __attribute__((ext_vector_type(4))) float f32x4;

__device__ __forceinline__ u16 f2bf(float f) {
  unsigned int u = __float_as_uint(f);
  u += 0x7fffu + ((u >> 16) & 1u);   // round-to-nearest-even
  return (u16)(u >> 16);
}

__device__ __forceinline__ void gload16(const u16* g, u16* l) {
  __builtin_amdgcn_global_load_lds(
      (const __attribute__((address_space(1))) unsigned int*)(const void*)g,
      (__attribute__((address_space(3))) unsigned int*)(void*)l, 16, 0, 0);
}

// ---------------------------------------------------------------------------
// Kernel 1: x f32 -> bf16
// ---------------------------------------------------------------------------
__global__ __launch_bounds__(256) void convert_x_kernel(const float* __restrict__ X,
                                                        u16* __restrict__ Xb) {
  int i = blockIdx.x * 256 + threadIdx.x;
  float4 v = ((const float4*)X)[i];
  ushort4 o;
  o.x = f2bf(v.x); o.y = f2bf(v.y); o.z = f2bf(v.z); o.w = f2bf(v.w);
  ((ushort4*)Xb)[i] = o;
}

// ---------------------------------------------------------------------------
// Kernel 2: Wt[h][s][d] = bf16(proj_w[h][d][s])
// ---------------------------------------------------------------------------
__global__ __launch_bounds__(256) void transpose_w_kernel(const float* __restrict__ W,
                                                          u16* __restrict__ Wt) {
  __shared__ float tile[64][65];
  int h  = blockIdx.z;
  int s0 = blockIdx.x * 64;
  int d0 = blockIdx.y * 64;
  int t  = threadIdx.x;
  int tr = t >> 4;
  int tc = t & 15;
#pragma unroll
  for (int i = 0; i < 4; ++i) {
    int d = tr + i * 16;
    float4 v = *(const float4*)(W + ((size_t)h * ND + d0 + d) * ND + s0 + tc * 4);
    tile[d][tc * 4 + 0] = v.x;
    tile[d][tc * 4 + 1] = v.y;
    tile[d][tc * 4 + 2] = v.z;
    tile[d][tc * 4 + 3] = v.w;
  }
  __syncthreads();
#pragma unroll
  for (int i = 0; i < 4; ++i) {
    int s  = tr + i * 16;
    int dd = tc * 4;
    ushort4 o;
    o.x = f2bf(tile[dd + 0][s]);
    o.y = f2bf(tile[dd + 1][s]);
    o.z = f2bf(tile[dd + 2][s]);
    o.w = f2bf(tile[dd + 3][s]);
    *(ushort4*)(Wt + ((size_t)h * ND + s0 + s) * ND + d0 + dd) = o;
  }
}

// ---------------------------------------------------------------------------
// Kernel 3: A[h,o,d] = sum_{j>=d} out_w[o,j]*mix_w[h,j]  (suffix scan) + Kc
// ---------------------------------------------------------------------------
__global__ __launch_bounds__(256) void scan_kernel(const float* __restrict__ out_w,
                                                   const float* __restrict__ mix_w,
                                                   const float* __restrict__ mix_b,
                                                   const float* __restrict__ proj_b,
                                                   const float* __restrict__ out_b,
                                                   u16* __restrict__ Afac,
                                                   float* __restrict__ Kc) {
  int h = blockIdx.x >> 10;
  int o = blockIdx.x & 1023;
  int t = threadIdx.x;
  int lane = t & 63, wave = t >> 6;
  const float* owr = out_w + (size_t)o * ND;
  const float* mwr = mix_w + (size_t)h * ND;
  const float* mbr = mix_b + (size_t)h * ND;
  const float* pbr = proj_b + (size_t)h * ND;

  float l[4];
  float run = 0.f, mbdot = 0.f;
#pragma unroll
  for (int k = 0; k < 4; ++k) {
    int j = 1023 - (4 * t + k);
    float ow = owr[j];
    mbdot += ow * mbr[j];
    run += ow * mwr[j];
    l[k] = run;
  }
  float tsum = run;
  float sc = tsum;
#pragma unroll
  for (int d = 1; d < 64; d <<= 1) {
    float other = __shfl_up(sc, d);
    if (lane >= d) sc += other;
  }
  __shared__ float wsum[4];
  __shared__ float red[4];
  if (lane == 63) wsum[wave] = sc;
  __syncthreads();
  float wprefix = 0.f;
  for (int w = 0; w < wave; ++w) wprefix += wsum[w];
  float excl = wprefix + sc - tsum;

  float cdot = 0.f;
  ushort4 pack;
  u16* pk = (u16*)&pack;
#pragma unroll
  for (int k = 0; k < 4; ++k) {
    int d = 1023 - (4 * t + k);
    float a = excl + l[k];
    cdot += a * pbr[d];
    pk[3 - k] = f2bf(a);
  }
  *(ushort4*)(Afac + ((size_t)(h * ND + o)) * ND + (1020 - 4 * t)) = pack;

  float tot = cdot + mbdot;
#pragma unroll
  for (int m = 32; m >= 1; m >>= 1) tot += __shfl_xor(tot, m);
  if (lane == 0) red[wave] = tot;
  __syncthreads();
  if (t == 0) {
    Kc[h * ND + o] = red[0] + red[1] + red[2] + red[3] + out_b[o];
  }
}

// ---------------------------------------------------------------------------
// Old-style 128x128 BT GEMM core (used for gemm1 only)
// ---------------------------------------------------------------------------
__device__ __forceinline__ void gemm_core(const u16* __restrict__ Ag,
                                          const u16* __restrict__ Bg,
                                          u16* As, u16* Bs,
                                          f32x4 acc[4][4]) {
  const int t    = threadIdx.x;
  const int lane = t & 63;
  const int wave = t >> 6;
  const int wm   = (wave >> 1) * 64;
  const int wn   = (wave & 1) * 64;
  const int row0 = t >> 2;
  const int kc0  = (t & 3) * 8;
  u16* dA0 = As + t * 8;
  u16* dA1 = As + 2048 + t * 8;
  u16* dB0 = Bs + t * 8;
  u16* dB1 = Bs + 2048 + t * 8;
  const int arow  = wm + (lane & 15);
  const int brow  = wn + (lane & 15);
  const int kfrag = (lane >> 4) * 8;

  for (int kk = 0; kk < 1024; kk += 32) {
    __syncthreads();
    gload16(Ag + (size_t)row0 * 1024 + kk + kc0, dA0);
    gload16(Ag + (size_t)(row0 + 64) * 1024 + kk + kc0, dA1);
    gload16(Bg + (size_t)row0 * 1024 + kk + kc0, dB0);
    gload16(Bg + (size_t)(row0 + 64) * 1024 + kk + kc0, dB1);
    __syncthreads();
    short8 af[4], bf[4];
#pragma unroll
    for (int mi = 0; mi < 4; ++mi)
      af[mi] = *(const short8*)(As + (arow + mi * 16) * 32 + kfrag);
#pragma unroll
    for (int ni = 0; ni < 4; ++ni)
      bf[ni] = *(const short8*)(Bs + (brow + ni * 16) * 32 + kfrag);
#pragma unroll
    for (int mi = 0; mi < 4; ++mi)
#pragma unroll
      for (int ni = 0; ni < 4; ++ni)
        acc[mi][ni] = __builtin_amdgcn_mfma_f32_16x16x32_bf16(af[mi], bf[ni], acc[mi][ni], 0, 0, 0);
  }
}

// ---------------------------------------------------------------------------
// Kernel 4: M[h] = A[h] . Wt[h]^T -> bf16 M[h][o][s]
// Epilogue: LDS bounce (Cs, XOR-swizzled) -> full-line short8 stores.
// ---------------------------------------------------------------------------
__global__ __launch_bounds__(256) void gemm1_kernel(const u16* __restrict__ Afac,
                                                    const u16* __restrict__ Wt,
                                                    u16* __restrict__ Mmat) {
  __shared__ __align__(16) u16 As[128 * 32];
  __shared__ __align__(16) u16 Bs[128 * 32];
  __shared__ __align__(16) u16 Cs[128 * 128];
  int h  = blockIdx.z;
  int m0 = blockIdx.y * 128;
  int n0 = blockIdx.x * 128;
  const u16* Ag = Afac + ((size_t)h * ND + m0) * ND;
  const u16* Bg = Wt + ((size_t)h * ND + n0) * ND;
  f32x4 acc[4][4];
  f32x4 z = {0.f, 0.f, 0.f, 0.f};
#pragma unroll
  for (int i = 0; i < 4; ++i)
#pragma unroll
    for (int j = 0; j < 4; ++j) acc[i][j] = z;
  gemm_core(Ag, Bg, As, Bs, acc);

  const int t    = threadIdx.x;
  const int lane = t & 63;
  const int wave = t >> 6;
  const int wm = (wave >> 1) * 64, wn = (wave & 1) * 64;
  const int rg = lane >> 4;
  const int fr = lane & 15;
#pragma unroll
  for (int mi = 0; mi < 4; ++mi)
#pragma unroll
    for (int ni = 0; ni < 4; ++ni)
#pragma unroll
      for (int r = 0; r < 4; ++r) {
        int rl = wm + mi * 16 + rg * 4 + r;
        int c  = wn + ni * 16 + fr;
        Cs[rl * 128 + 8 * ((c >> 3) ^ (rl & 7)) + (c & 7)] = f2bf(acc[mi][ni][r]);
      }
  __syncthreads();
  u16* Mh = Mmat + (size_t)h * ND * ND;
#pragma unroll
  for (int rr = 0; rr < 4; ++rr) {
    int rl = rr * 32 + (t >> 3);
#pragma unroll
    for (int j = 0; j < 2; ++j) {
      int c8 = (t & 7) + 8 * j;
      short8 v = *(const short8*)(Cs + rl * 128 + 8 * (c8 ^ (rl & 7)));
      *(short8*)(Mh + (size_t)(m0 + rl) * ND + n0 + c8 * 8) = v;
    }
  }
}

// ---------------------------------------------------------------------------
// Kernel 5: 8-phase 256x256 GEMM, single round: 256 blocks, each block does
// TWO 256-wide n-tiles (one 512-col pair) over the same 256-row m-panel.
// C[4096 x 8192] = Xb[4096x1024] . Bm[8192x1024]^T (+bias Kc), b/h/e remap.
// Rect XCD swizzle: each XCD = 8 m-blocks x 4 n-pairs (8 MB unique fetch).
// Epilogue: direct wide stores (round-2 proven).
// ---------------------------------------------------------------------------
#define MFMA_(d, a, b) d = __builtin_amdgcn_mfma_f32_16x16x32_bf16(a, b, d, 0, 0, 0)
#define NOVM ((void)0)
#define VM6 asm volatile("s_waitcnt vmcnt(6)" ::: "memory")
#define VM0 asm volatile("s_waitcnt vmcnt(0)" ::: "memory")

#define PHASE(q, b, STAGE_STMT, VMSTMT) do {                                   \
    short8 a00 = ldA(b, 2*(q),     0);                                         \
    short8 a01 = ldA(b, 2*(q),     1);                                         \
    short8 a10 = ldA(b, 2*(q) + 1, 0);                                         \
    short8 a11 = ldA(b, 2*(q) + 1, 1);                                         \
    if ((q) == 0) {                                                            \
      bf00 = ldB(b, 0, 0); bf01 = ldB(b, 0, 1);                                \
      bf10 = ldB(b, 1, 0); bf11 = ldB(b, 1, 1);                                \
      bf20 = ldB(b, 2, 0); bf21 = ldB(b, 2, 1);                                \
      bf30 = ldB(b, 3, 0); bf31 = ldB(b, 3, 1);                                \
    }                                                                          \
    STAGE_STMT;                                                                \
    __builtin_amdgcn_sched_barrier(0);                                         \
    VMSTMT;                                                                    \
    __builtin_amdgcn_s_barrier();                                              \
    asm volatile("s_waitcnt lgkmcnt(0)" ::: "memory");                         \
    __builtin_amdgcn_sched_barrier(0);                                         \
    __builtin_amdgcn_s_setprio(1);                                             \
    MFMA_(acc[2*(q)  ][0], a00, bf00);                                         \
    MFMA_(acc[2*(q)  ][1], a00, bf10);                                         \
    MFMA_(acc[2*(q)  ][2], a00, bf20);                                         \
    MFMA_(acc[2*(q)  ][3], a00, bf30);                                         \
    MFMA_(acc[2*(q)+1][0], a10, bf00);                                         \
    MFMA_(acc[2*(q)+1][1], a10, bf10);                                         \
    MFMA_(acc[2*(q)+1][2], a10, bf20);                                         \
    MFMA_(acc[2*(q)+1][3], a10, bf30);                                         \
    MFMA_(acc[2*(q)  ][0], a01, bf01);                                         \
    MFMA_(acc[2*(q)  ][1], a01, bf11);                                         \
    MFMA_(acc[2*(q)  ][2], a01, bf21);                                         \
    MFMA_(acc[2*(q)  ][3], a01, bf31);                                         \
    MFMA_(acc[2*(q)+1][0], a11, bf01);                                         \
    MFMA_(acc[2*(q)+1][1], a11, bf11);                                         \
    MFMA_(acc[2*(q)+1][2], a11, bf21);                                         \
    MFMA_(acc[2*(q)+1][3], a11, bf31);                                         \
    __builtin_amdgcn_s_setprio(0);                                             \
    __builtin_amdgcn_s_barrier();                                              \
  } while (0)

__global__ __launch_bounds__(512, 2) void gemm2_8ph(const u16* __restrict__ Xb,
                                                    const u16* __restrict__ Bm,
                                                    const float* __restrict__ Kc,
                                                    float* __restrict__ Out) {
  __shared__ __align__(16) u16 lds[65536];   // 128 KiB: [buf][A 16K u16 | B 16K u16]
  const int tid  = threadIdx.x;
  const int lane = tid & 63;
  const int wave = tid >> 6;
  const int wm   = wave >> 2;     // 0..1
  const int wn   = wave & 3;      // 0..3

  // Rect XCD swizzle: 256 blocks; xcd = bid&7 owns an 8m x 4npair rectangle.
  const int bid   = blockIdx.x;
  const int xcd   = bid & 7;
  const int loc   = bid >> 3;                    // [0,32)
  const int mb    = (xcd >> 2) * 8 + (loc >> 2); // [0,16)
  const int npair = (xcd & 3) * 4 + (loc & 3);   // [0,16)
  const int m0    = mb * 256;

  // staging: lane i covers row li8 = i>>3, phys chunk i&7, logical chunk
  // lc = (i&7) ^ li8 (inverse swizzle applied on global src; LDS dst linear)
  const int li8 = lane >> 3;
  const int lc  = (lane & 7) ^ li8;
  const size_t stSrc = (size_t)li8 * ND + lc * 8;  // u16
  const int stDst = lane * 8;                      // u16

  const u16* aSrc = Xb + (size_t)m0 * ND + stSrc;

  const int fr  = lane & 15;
  const int rg  = lane >> 4;
  const int ca0 = (((lane >> 4)    ) ^ (lane & 7)) * 8;  // u16
  const int ca1 = (((lane >> 4) + 4) ^ (lane & 7)) * 8;
  const int aOff = (wm * 128 + fr) * 64;
  const int bOff = 16384 + (wn * 64 + fr) * 64;

  f32x4 acc[8][4];
  const f32x4 z = {0.f, 0.f, 0.f, 0.f};
  short8 bf00, bf01, bf10, bf11, bf20, bf21, bf30, bf31;

  auto ldA = [&](int b, int mi, int kk) -> short8 {
    return *(const short8*)(lds + b * 32768 + aOff + mi * 1024 + (kk ? ca1 : ca0));
  };
  auto ldB = [&](int b, int ni, int kk) -> short8 {
    return *(const short8*)(lds + b * 32768 + bOff + ni * 1024 + (kk ? ca1 : ca0));
  };

#pragma unroll 1
  for (int hf = 0; hf < 2; ++hf) {
    const int n0 = npair * 512 + hf * 256;
    const u16* bSrc = Bm + (size_t)n0 * ND + stSrc;

    auto stageA = [&](int h, int t, int b) {   // interleaved half h
#pragma unroll
      for (int jj = 0; jj < 2; ++jj) {
        int j = 2 * wave + jj;
        int R = ((j >> 3) << 7) + h * 64 + ((j & 7) << 3);
        gload16(aSrc + (size_t)R * ND + t * 64, lds + b * 32768 + R * 64 + stDst);
      }
    };
    auto stageB = [&](int h, int t, int b) {   // plain half h
#pragma unroll
      for (int jj = 0; jj < 2; ++jj) {
        int j = 2 * wave + jj;
        int R = h * 128 + j * 8;
        gload16(bSrc + (size_t)R * ND + t * 64, lds + b * 32768 + 16384 + R * 64 + stDst);
      }
    };

#pragma unroll
    for (int i = 0; i < 8; ++i)
#pragma unroll
      for (int j = 0; j < 4; ++j) acc[i][j] = z;

    // Prologue: tile0 (4 halves) + 3 halves of tile1
    stageA(0, 0, 0); stageA(1, 0, 0);
    stageB(0, 0, 0); stageB(1, 0, 0);
    stageB(0, 1, 1); stageB(1, 1, 1);
    stageA(0, 1, 1);
    VM6;
    __builtin_amdgcn_s_barrier();

    // 16 K-tiles (K=1024, BK=64)
#pragma unroll 1
    for (int it = 0; it < 7; ++it) {
      const int T = 2 * it;
      PHASE(0, 0, stageA(1, T + 1, 1), NOVM);
      PHASE(1, 0, stageB(0, T + 2, 0), NOVM);
      PHASE(2, 0, stageB(1, T + 2, 0), NOVM);
      PHASE(3, 0, stageA(0, T + 2, 0), VM6);
      PHASE(0, 1, stageA(1, T + 2, 0), NOVM);
      PHASE(1, 1, stageB(0, T + 3, 1), NOVM);
      PHASE(2, 1, stageB(1, T + 3, 1), NOVM);
      PHASE(3, 1, stageA(0, T + 3, 1), VM6);
    }
    // Tail: tiles 14 (buf0) and 15 (buf1)
    PHASE(0, 0, stageA(1, 15, 1), NOVM);
    PHASE(1, 0, NOVM, NOVM);
    PHASE(2, 0, NOVM, NOVM);
    PHASE(3, 0, NOVM, VM0);
    PHASE(0, 1, NOVM, NOVM);
    PHASE(1, 1, NOVM, NOVM);
    PHASE(2, 1, NOVM, NOVM);
    PHASE(3, 1, NOVM, NOVM);

    // Epilogue: direct wide stores (4x 64B segments per instr), bias added.
    const int hH = n0 >> 10;
    const int o0 = (n0 & 1023) + wn * 64 + fr;
    const int r0 = m0 + wm * 128 + rg * 4;
    float bias[4];
#pragma unroll
    for (int ni = 0; ni < 4; ++ni) bias[ni] = Kc[hH * 1024 + o0 + ni * 16];
#pragma unroll
    for (int mi = 0; mi < 8; ++mi) {
#pragma unroll
      for (int r = 0; r < 4; ++r) {
        int rb = r0 + mi * 16 + r;            // global x row = b*512 + e
        float* orow = Out + ((size_t)(rb >> 9) * 4096 + hH * 512 + (rb & 511)) * 1024 + o0;
#pragma unroll
        for (int ni = 0; ni < 4; ++ni)
          orow[ni * 16] = acc[mi][ni][r] + bias[ni];
      }
    }
  }
}

// ---------------------------------------------------------------------------
extern "C" void kernel_launch(void* const* d_in, const int* in_sizes, int n_in,
                              void* d_out, int out_size, void* d_ws, size_t ws_size,
                              hipStream_t stream) {
  (void)in_sizes; (void)n_in; (void)out_size; (void)ws_size;
  const float* x      = (const float*)d_in[0];
  const float* proj_w = (const float*)d_in[1];
  const float* proj_b = (const float*)d_in[2];
  const float* mix_w  = (const float*)d_in[3];
  const float* mix_b  = (const float*)d_in[4];
  const float* out_w  = (const float*)d_in[5];
  const float* out_b  = (const float*)d_in[6];
  float* Out = (float*)d_out;

  // Scratch carved from d_out (dead before gemm2 writes Out): Wt, Afac
  u16* Wt   = (u16*)d_out;
  u16* Afac = (u16*)d_out + (size_t)8 * 1024 * 1024;
  // Scratch in d_ws: Xb (8 MiB) + Mmat (16 MiB) + Kc (32 KiB)
  u16*   Xb   = (u16*)d_ws;
  u16*   Mmat = (u16*)((char*)d_ws + ((size_t)8 << 20));
  float* Kc   = (float*)((char*)d_ws + ((size_t)24 << 20));

  convert_x_kernel<<<4096, 256, 0, stream>>>(x, Xb);
  transpose_w_kernel<<<dim3(16, 16, NH), 256, 0, stream>>>(proj_w, Wt);
  scan_kernel<<<NH * ND, 256, 0, stream>>>(out_w, mix_w, mix_b, proj_b, out_b, Afac, Kc);
  gemm1_kernel<<<dim3(8, 8, NH), 256, 0, stream>>>(Afac, Wt, Mmat);
  gemm2_8ph<<<256, 512, 0, stream>>>(Xb, Mmat, Kc, Out);
}

// Round 5
// 131.843 us; speedup vs baseline: 1.1380x; 1.1380x over previous
//
#include <hip/hip_runtime.h>

// Problem constants (S == DIM == HID == 1024)
#define NH    8      // heads
#define NE    512    // experts per head-group (E)
#define NB    8      // batch
#define ND    1024   // DIM == HID == S
#define NROW  4096   // NB * NE  (rows of x)

typedef unsigned short u16;
typedef __attribute__((ext_vector_type(8))) short short8;
typedef __attribute__((ext_vector_type(4))) float f32x4;

__device__ __forceinline__ u16 f2bf(float f) {
  unsigned int u = __float_as_uint(f);
  u += 0x7fffu + ((u >> 16) & 1u);   // round-to-nearest-even
  return (u16)(u >> 16);
}

__device__ __forceinline__ void gload16(const u16* g, u16* l) {
  __builtin_amdgcn_global_load_lds(
      (const __attribute__((address_space(1))) unsigned int*)(const void*)g,
      (__attribute__((address_space(3))) unsigned int*)(void*)l, 16, 0, 0);
}

// ---------------------------------------------------------------------------
// Kernel 1: x f32 -> bf16
// ---------------------------------------------------------------------------
__global__ __launch_bounds__(256) void convert_x_kernel(const float* __restrict__ X,
                                                        u16* __restrict__ Xb) {
  int i = blockIdx.x * 256 + threadIdx.x;
  float4 v = ((const float4*)X)[i];
  ushort4 o;
  o.x = f2bf(v.x); o.y = f2bf(v.y); o.z = f2bf(v.z); o.w = f2bf(v.w);
  ((ushort4*)Xb)[i] = o;
}

// ---------------------------------------------------------------------------
// Kernel 2: Wt[h][s][d] = bf16(proj_w[h][d][s])
// ---------------------------------------------------------------------------
__global__ __launch_bounds__(256) void transpose_w_kernel(const float* __restrict__ W,
                                                          u16* __restrict__ Wt) {
  __shared__ float tile[64][65];
  int h  = blockIdx.z;
  int s0 = blockIdx.x * 64;
  int d0 = blockIdx.y * 64;
  int t  = threadIdx.x;
  int tr = t >> 4;
  int tc = t & 15;
#pragma unroll
  for (int i = 0; i < 4; ++i) {
    int d = tr + i * 16;
    float4 v = *(const float4*)(W + ((size_t)h * ND + d0 + d) * ND + s0 + tc * 4);
    tile[d][tc * 4 + 0] = v.x;
    tile[d][tc * 4 + 1] = v.y;
    tile[d][tc * 4 + 2] = v.z;
    tile[d][tc * 4 + 3] = v.w;
  }
  __syncthreads();
#pragma unroll
  for (int i = 0; i < 4; ++i) {
    int s  = tr + i * 16;
    int dd = tc * 4;
    ushort4 o;
    o.x = f2bf(tile[dd + 0][s]);
    o.y = f2bf(tile[dd + 1][s]);
    o.z = f2bf(tile[dd + 2][s]);
    o.w = f2bf(tile[dd + 3][s]);
    *(ushort4*)(Wt + ((size_t)h * ND + s0 + s) * ND + d0 + dd) = o;
  }
}

// ---------------------------------------------------------------------------
// Kernel 3: A[h,o,d] = sum_{j>=d} out_w[o,j]*mix_w[h,j]  (suffix scan) + Kc
// ---------------------------------------------------------------------------
__global__ __launch_bounds__(256) void scan_kernel(const float* __restrict__ out_w,
                                                   const float* __restrict__ mix_w,
                                                   const float* __restrict__ mix_b,
                                                   const float* __restrict__ proj_b,
                                                   const float* __restrict__ out_b,
                                                   u16* __restrict__ Afac,
                                                   float* __restrict__ Kc) {
  int h = blockIdx.x >> 10;
  int o = blockIdx.x & 1023;
  int t = threadIdx.x;
  int lane = t & 63, wave = t >> 6;
  const float* owr = out_w + (size_t)o * ND;
  const float* mwr = mix_w + (size_t)h * ND;
  const float* mbr = mix_b + (size_t)h * ND;
  const float* pbr = proj_b + (size_t)h * ND;

  float l[4];
  float run = 0.f, mbdot = 0.f;
#pragma unroll
  for (int k = 0; k < 4; ++k) {
    int j = 1023 - (4 * t + k);
    float ow = owr[j];
    mbdot += ow * mbr[j];
    run += ow * mwr[j];
    l[k] = run;
  }
  float tsum = run;
  float sc = tsum;
#pragma unroll
  for (int d = 1; d < 64; d <<= 1) {
    float other = __shfl_up(sc, d);
    if (lane >= d) sc += other;
  }
  __shared__ float wsum[4];
  __shared__ float red[4];
  if (lane == 63) wsum[wave] = sc;
  __syncthreads();
  float wprefix = 0.f;
  for (int w = 0; w < wave; ++w) wprefix += wsum[w];
  float excl = wprefix + sc - tsum;

  float cdot = 0.f;
  ushort4 pack;
  u16* pk = (u16*)&pack;
#pragma unroll
  for (int k = 0; k < 4; ++k) {
    int d = 1023 - (4 * t + k);
    float a = excl + l[k];
    cdot += a * pbr[d];
    pk[3 - k] = f2bf(a);
  }
  *(ushort4*)(Afac + ((size_t)(h * ND + o)) * ND + (1020 - 4 * t)) = pack;

  float tot = cdot + mbdot;
#pragma unroll
  for (int m = 32; m >= 1; m >>= 1) tot += __shfl_xor(tot, m);
  if (lane == 0) red[wave] = tot;
  __syncthreads();
  if (t == 0) {
    Kc[h * ND + o] = red[0] + red[1] + red[2] + red[3] + out_b[o];
  }
}

// ---------------------------------------------------------------------------
// Shared 8-phase 256x256 K=1024 BT GEMM core (m201 template).
// 512 thr = 8 waves (2M x 4N); wave tile 128x64; BK=64; LDS 128 KiB dbuf.
// LDS swizzle: 16B chunk p = c ^ (row&7), via pre-swizzled global src.
// ---------------------------------------------------------------------------
#define MFMA_(d, a, b) d = __builtin_amdgcn_mfma_f32_16x16x32_bf16(a, b, d, 0, 0, 0)
#define NOVM ((void)0)
#define VM6 asm volatile("s_waitcnt vmcnt(6)" ::: "memory")
#define VM0 asm volatile("s_waitcnt vmcnt(0)" ::: "memory")

#define PHASE(q, b, STAGE_STMT, VMSTMT) do {                                   \
    short8 a00 = ldA(b, 2*(q),     0);                                         \
    short8 a01 = ldA(b, 2*(q),     1);                                         \
    short8 a10 = ldA(b, 2*(q) + 1, 0);                                         \
    short8 a11 = ldA(b, 2*(q) + 1, 1);                                         \
    if ((q) == 0) {                                                            \
      bf00 = ldB(b, 0, 0); bf01 = ldB(b, 0, 1);                                \
      bf10 = ldB(b, 1, 0); bf11 = ldB(b, 1, 1);                                \
      bf20 = ldB(b, 2, 0); bf21 = ldB(b, 2, 1);                                \
      bf30 = ldB(b, 3, 0); bf31 = ldB(b, 3, 1);                                \
    }                                                                          \
    STAGE_STMT;                                                                \
    __builtin_amdgcn_sched_barrier(0);                                         \
    VMSTMT;                                                                    \
    __builtin_amdgcn_s_barrier();                                              \
    asm volatile("s_waitcnt lgkmcnt(0)" ::: "memory");                         \
    __builtin_amdgcn_sched_barrier(0);                                         \
    __builtin_amdgcn_s_setprio(1);                                             \
    MFMA_(acc[2*(q)  ][0], a00, bf00);                                         \
    MFMA_(acc[2*(q)  ][1], a00, bf10);                                         \
    MFMA_(acc[2*(q)  ][2], a00, bf20);                                         \
    MFMA_(acc[2*(q)  ][3], a00, bf30);                                         \
    MFMA_(acc[2*(q)+1][0], a10, bf00);                                         \
    MFMA_(acc[2*(q)+1][1], a10, bf10);                                         \
    MFMA_(acc[2*(q)+1][2], a10, bf20);                                         \
    MFMA_(acc[2*(q)+1][3], a10, bf30);                                         \
    MFMA_(acc[2*(q)  ][0], a01, bf01);                                         \
    MFMA_(acc[2*(q)  ][1], a01, bf11);                                         \
    MFMA_(acc[2*(q)  ][2], a01, bf21);                                         \
    MFMA_(acc[2*(q)  ][3], a01, bf31);                                         \
    MFMA_(acc[2*(q)+1][0], a11, bf01);                                         \
    MFMA_(acc[2*(q)+1][1], a11, bf11);                                         \
    MFMA_(acc[2*(q)+1][2], a11, bf21);                                         \
    MFMA_(acc[2*(q)+1][3], a11, bf31);                                         \
    __builtin_amdgcn_s_setprio(0);                                             \
    __builtin_amdgcn_s_barrier();                                              \
  } while (0)

// Common per-thread geometry + staging/read lambdas + full K-loop, as a macro
// so both gemm kernels share the exact schedule.
#define GEMM_8PH_BODY(ASRC, BSRC)                                              \
  const int tid  = threadIdx.x;                                                \
  const int lane = tid & 63;                                                   \
  const int wave = tid >> 6;                                                   \
  const int wm   = wave >> 2;                                                  \
  const int wn   = wave & 3;                                                   \
  const int li8 = lane >> 3;                                                   \
  const int lc  = (lane & 7) ^ li8;                                            \
  const size_t stSrc = (size_t)li8 * ND + lc * 8;                              \
  const int stDst = lane * 8;                                                  \
  const u16* aSrc = (ASRC) + stSrc;                                            \
  const u16* bSrc = (BSRC) + stSrc;                                            \
  const int fr  = lane & 15;                                                   \
  const int rg  = lane >> 4;                                                   \
  const int ca0 = (((lane >> 4)    ) ^ (lane & 7)) * 8;                        \
  const int ca1 = (((lane >> 4) + 4) ^ (lane & 7)) * 8;                        \
  const int aOff = (wm * 128 + fr) * 64;                                       \
  const int bOff = 16384 + (wn * 64 + fr) * 64;                                \
  auto stageA = [&](int h, int t, int b) {                                     \
    _Pragma("unroll")                                                          \
    for (int jj = 0; jj < 2; ++jj) {                                           \
      int j = 2 * wave + jj;                                                   \
      int R = ((j >> 3) << 7) + h * 64 + ((j & 7) << 3);                       \
      gload16(aSrc + (size_t)R * ND + t * 64, lds + b * 32768 + R * 64 + stDst); \
    }                                                                          \
  };                                                                           \
  auto stageB = [&](int h, int t, int b) {                                     \
    _Pragma("unroll")                                                          \
    for (int jj = 0; jj < 2; ++jj) {                                           \
      int j = 2 * wave + jj;                                                   \
      int R = h * 128 + j * 8;                                                 \
      gload16(bSrc + (size_t)R * ND + t * 64, lds + b * 32768 + 16384 + R * 64 + stDst); \
    }                                                                          \
  };                                                                           \
  auto ldA = [&](int b, int mi, int kk) -> short8 {                            \
    return *(const short8*)(lds + b * 32768 + aOff + mi * 1024 + (kk ? ca1 : ca0)); \
  };                                                                           \
  auto ldB = [&](int b, int ni, int kk) -> short8 {                            \
    return *(const short8*)(lds + b * 32768 + bOff + ni * 1024 + (kk ? ca1 : ca0)); \
  };                                                                           \
  f32x4 acc[8][4];                                                             \
  f32x4 z = {0.f, 0.f, 0.f, 0.f};                                              \
  _Pragma("unroll")                                                            \
  for (int i = 0; i < 8; ++i)                                                  \
    _Pragma("unroll")                                                          \
    for (int j = 0; j < 4; ++j) acc[i][j] = z;                                 \
  short8 bf00, bf01, bf10, bf11, bf20, bf21, bf30, bf31;                       \
  stageA(0, 0, 0); stageA(1, 0, 0);                                            \
  stageB(0, 0, 0); stageB(1, 0, 0);                                            \
  stageB(0, 1, 1); stageB(1, 1, 1);                                            \
  stageA(0, 1, 1);                                                             \
  asm volatile("s_waitcnt vmcnt(6)" ::: "memory");                             \
  __builtin_amdgcn_s_barrier();                                                \
  _Pragma("unroll 1")                                                          \
  for (int it = 0; it < 7; ++it) {                                             \
    const int T = 2 * it;                                                      \
    PHASE(0, 0, stageA(1, T + 1, 1), NOVM);                                    \
    PHASE(1, 0, stageB(0, T + 2, 0), NOVM);                                    \
    PHASE(2, 0, stageB(1, T + 2, 0), NOVM);                                    \
    PHASE(3, 0, stageA(0, T + 2, 0), VM6);                                     \
    PHASE(0, 1, stageA(1, T + 2, 0), NOVM);                                    \
    PHASE(1, 1, stageB(0, T + 3, 1), NOVM);                                    \
    PHASE(2, 1, stageB(1, T + 3, 1), NOVM);                                    \
    PHASE(3, 1, stageA(0, T + 3, 1), VM6);                                     \
  }                                                                            \
  PHASE(0, 0, stageA(1, 15, 1), NOVM);                                         \
  PHASE(1, 0, NOVM, NOVM);                                                     \
  PHASE(2, 0, NOVM, NOVM);                                                     \
  PHASE(3, 0, NOVM, VM0);                                                      \
  PHASE(0, 1, NOVM, NOVM);                                                     \
  PHASE(1, 1, NOVM, NOVM);                                                     \
  PHASE(2, 1, NOVM, NOVM);                                                     \
  PHASE(3, 1, NOVM, NOVM);

// ---------------------------------------------------------------------------
// Kernel 4: gemm1_8ph — per head h: M[h] = A[h] (o x d) . W[h] (d x s),
// B-operand rows = s via Wt[h][s][d]. Grid (4 n, 4 m, 8 h) = 128 blocks.
// ---------------------------------------------------------------------------
__global__ __launch_bounds__(512, 2) void gemm1_8ph(const u16* __restrict__ Afac,
                                                    const u16* __restrict__ Wt,
                                                    u16* __restrict__ Mmat) {
  __shared__ __align__(16) u16 lds[65536];
  const int h  = blockIdx.z;
  const int m0 = blockIdx.y * 256;
  const int n0 = blockIdx.x * 256;
  GEMM_8PH_BODY(Afac + ((size_t)h * ND + m0) * ND, Wt + ((size_t)h * ND + n0) * ND)

  // Epilogue: direct bf16 stores.
  u16* Mh = Mmat + (size_t)h * ND * ND;
  const int r0 = m0 + wm * 128 + rg * 4;
  const int c0 = n0 + wn * 64 + fr;
#pragma unroll
  for (int mi = 0; mi < 8; ++mi) {
#pragma unroll
    for (int r = 0; r < 4; ++r) {
      u16* orow = Mh + (size_t)(r0 + mi * 16 + r) * ND + c0;
#pragma unroll
      for (int ni = 0; ni < 4; ++ni)
        orow[ni * 16] = f2bf(acc[mi][ni][r]);
    }
  }
}

// ---------------------------------------------------------------------------
// Kernel 5: gemm2_8ph (round-2 proven config).
// C[4096 x 8192] = Xb[4096x1024] . Bm[8192x1024]^T (+bias Kc), b/h/e remap.
// 512 blocks, XCD swizzle, direct wide stores.
// ---------------------------------------------------------------------------
__global__ __launch_bounds__(512, 2) void gemm2_8ph(const u16* __restrict__ Xb,
                                                    const u16* __restrict__ Bm,
                                                    const float* __restrict__ Kc,
                                                    float* __restrict__ Out) {
  __shared__ __align__(16) u16 lds[65536];
  // XCD-aware block swizzle (512 blocks, 512 % 8 == 0 -> bijective)
  const int bid = blockIdx.x;
  const int swz = (bid & 7) * 64 + (bid >> 3);
  const int m0  = (swz >> 5) * 256;     // 16 m-blocks
  const int n0  = (swz & 31) * 256;     // 32 n-blocks
  GEMM_8PH_BODY(Xb + (size_t)m0 * ND, Bm + (size_t)n0 * ND)

  // Epilogue: bias + b/h/e remap, direct stores.
  const int hH = n0 >> 10;
  const int r0 = m0 + wm * 128 + rg * 4;
  const int c0 = n0 + wn * 64 + fr;
  const int o0 = c0 & 1023;
  float bias[4];
#pragma unroll
  for (int ni = 0; ni < 4; ++ni) bias[ni] = Kc[c0 + ni * 16];
#pragma unroll
  for (int mi = 0; mi < 8; ++mi) {
#pragma unroll
    for (int r = 0; r < 4; ++r) {
      int rb = r0 + mi * 16 + r;              // global x row = b*512 + e
      float* orow = Out + ((size_t)(rb >> 9) * 4096 + hH * 512 + (rb & 511)) * 1024 + o0;
#pragma unroll
      for (int ni = 0; ni < 4; ++ni)
        orow[ni * 16] = acc[mi][ni][r] + bias[ni];
    }
  }
}

// ---------------------------------------------------------------------------
extern "C" void kernel_launch(void* const* d_in, const int* in_sizes, int n_in,
                              void* d_out, int out_size, void* d_ws, size_t ws_size,
                              hipStream_t stream) {
  (void)in_sizes; (void)n_in; (void)out_size; (void)ws_size;
  const float* x      = (const float*)d_in[0];
  const float* proj_w = (const float*)d_in[1];
  const float* proj_b = (const float*)d_in[2];
  const float* mix_w  = (const float*)d_in[3];
  const float* mix_b  = (const float*)d_in[4];
  const float* out_w  = (const float*)d_in[5];
  const float* out_b  = (const float*)d_in[6];
  float* Out = (float*)d_out;

  // Scratch carved from d_out (dead before gemm2 writes Out): Wt, Afac
  u16* Wt   = (u16*)d_out;
  u16* Afac = (u16*)d_out + (size_t)8 * 1024 * 1024;
  // Scratch in d_ws: Xb (8 MiB) + Mmat (16 MiB) + Kc (32 KiB)
  u16*   Xb   = (u16*)d_ws;
  u16*   Mmat = (u16*)((char*)d_ws + ((size_t)8 << 20));
  float* Kc   = (float*)((char*)d_ws + ((size_t)24 << 20));

  convert_x_kernel<<<4096, 256, 0, stream>>>(x, Xb);
  transpose_w_kernel<<<dim3(16, 16, NH), 256, 0, stream>>>(proj_w, Wt);
  scan_kernel<<<NH * ND, 256, 0, stream>>>(out_w, mix_w, mix_b, proj_b, out_b, Afac, Kc);
  gemm1_8ph<<<dim3(4, 4, NH), 512, 0, stream>>>(Afac, Wt, Mmat);
  gemm2_8ph<<<512, 512, 0, stream>>>(Xb, Mmat, Kc, Out);
}

// Round 6
// 128.209 us; speedup vs baseline: 1.1703x; 1.0283x over previous
//
#include <hip/hip_runtime.h>

// Problem constants (S == DIM == HID == 1024)
#define NH    8      // heads
#define NE    512    // experts per head-group (E)
#define NB    8      // batch
#define ND    1024   // DIM == HID == S
#define NROW  4096   // NB * NE  (rows of x)

typedef unsigned short u16;
typedef __attribute__((ext_vector_type(8))) short short8;
typedef __attribute__((ext_vector_type(4))) float f32x4;

__device__ __forceinline__ u16 f2bf(float f) {
  unsigned int u = __float_as_uint(f);
  u += 0x7fffu + ((u >> 16) & 1u);   // round-to-nearest-even
  return (u16)(u >> 16);
}

__device__ __forceinline__ void gload16(const u16* g, u16* l) {
  __builtin_amdgcn_global_load_lds(
      (const __attribute__((address_space(1))) unsigned int*)(const void*)g,
      (__attribute__((address_space(3))) unsigned int*)(void*)l, 16, 0, 0);
}

// ---------------------------------------------------------------------------
// Kernel 1: x f32 -> bf16
// ---------------------------------------------------------------------------
__global__ __launch_bounds__(256) void convert_x_kernel(const float* __restrict__ X,
                                                        u16* __restrict__ Xb) {
  int i = blockIdx.x * 256 + threadIdx.x;
  float4 v = ((const float4*)X)[i];
  ushort4 o;
  o.x = f2bf(v.x); o.y = f2bf(v.y); o.z = f2bf(v.z); o.w = f2bf(v.w);
  ((ushort4*)Xb)[i] = o;
}

// ---------------------------------------------------------------------------
// Kernel 2: Wt[h][s][d] = bf16(proj_w[h][d][s])
// ---------------------------------------------------------------------------
__global__ __launch_bounds__(256) void transpose_w_kernel(const float* __restrict__ W,
                                                          u16* __restrict__ Wt) {
  __shared__ float tile[64][65];
  int h  = blockIdx.z;
  int s0 = blockIdx.x * 64;
  int d0 = blockIdx.y * 64;
  int t  = threadIdx.x;
  int tr = t >> 4;
  int tc = t & 15;
#pragma unroll
  for (int i = 0; i < 4; ++i) {
    int d = tr + i * 16;
    float4 v = *(const float4*)(W + ((size_t)h * ND + d0 + d) * ND + s0 + tc * 4);
    tile[d][tc * 4 + 0] = v.x;
    tile[d][tc * 4 + 1] = v.y;
    tile[d][tc * 4 + 2] = v.z;
    tile[d][tc * 4 + 3] = v.w;
  }
  __syncthreads();
#pragma unroll
  for (int i = 0; i < 4; ++i) {
    int s  = tr + i * 16;
    int dd = tc * 4;
    ushort4 o;
    o.x = f2bf(tile[dd + 0][s]);
    o.y = f2bf(tile[dd + 1][s]);
    o.z = f2bf(tile[dd + 2][s]);
    o.w = f2bf(tile[dd + 3][s]);
    *(ushort4*)(Wt + ((size_t)h * ND + s0 + s) * ND + d0 + dd) = o;
  }
}

// ---------------------------------------------------------------------------
// Kernel 3 (v2): one block per o; loop h inside so out_w[o,:] is read once.
// A[h,o,d] = sum_{j>=d} out_w[o,j]*mix_w[h,j]  (suffix scan) + Kc[h,o]
// ---------------------------------------------------------------------------
__global__ __launch_bounds__(256) void scan2_kernel(const float* __restrict__ out_w,
                                                    const float* __restrict__ mix_w,
                                                    const float* __restrict__ mix_b,
                                                    const float* __restrict__ proj_b,
                                                    const float* __restrict__ out_b,
                                                    u16* __restrict__ Afac,
                                                    float* __restrict__ Kc) {
  int o = blockIdx.x;
  int t = threadIdx.x;
  int lane = t & 63, wave = t >> 6;
  __shared__ float wsum[4];
  __shared__ float red[4];

  float ow[4];
#pragma unroll
  for (int k = 0; k < 4; ++k) ow[k] = out_w[(size_t)o * ND + 1023 - (4 * t + k)];
  float ob = out_b[o];

#pragma unroll 1
  for (int h = 0; h < NH; ++h) {
    const float* mwr = mix_w + (size_t)h * ND;
    const float* mbr = mix_b + (size_t)h * ND;
    const float* pbr = proj_b + (size_t)h * ND;

    float l[4];
    float run = 0.f, mbdot = 0.f;
#pragma unroll
    for (int k = 0; k < 4; ++k) {
      int j = 1023 - (4 * t + k);        // reversed order
      mbdot += ow[k] * mbr[j];
      run += ow[k] * mwr[j];
      l[k] = run;
    }
    float tsum = run;
    float sc = tsum;
#pragma unroll
    for (int d = 1; d < 64; d <<= 1) {
      float other = __shfl_up(sc, d);
      if (lane >= d) sc += other;
    }
    if (lane == 63) wsum[wave] = sc;
    __syncthreads();
    float wprefix = 0.f;
    for (int w = 0; w < wave; ++w) wprefix += wsum[w];
    float excl = wprefix + sc - tsum;

    float cdot = 0.f;
    ushort4 pack;
    u16* pk = (u16*)&pack;
#pragma unroll
    for (int k = 0; k < 4; ++k) {
      int d = 1023 - (4 * t + k);
      float a = excl + l[k];
      cdot += a * pbr[d];
      pk[3 - k] = f2bf(a);
    }
    *(ushort4*)(Afac + ((size_t)(h * ND + o)) * ND + (1020 - 4 * t)) = pack;

    float tot = cdot + mbdot;
#pragma unroll
    for (int m = 32; m >= 1; m >>= 1) tot += __shfl_xor(tot, m);
    if (lane == 0) red[wave] = tot;
    __syncthreads();
    if (t == 0) Kc[h * ND + o] = red[0] + red[1] + red[2] + red[3] + ob;
  }
}

// ---------------------------------------------------------------------------
// Shared defs for 8-phase cores
// ---------------------------------------------------------------------------
#define MFMA_(d, a, b) d = __builtin_amdgcn_mfma_f32_16x16x32_bf16(a, b, d, 0, 0, 0)
#define NOVM ((void)0)
#define VM6 asm volatile("s_waitcnt vmcnt(6)" ::: "memory")
#define VM5 asm volatile("s_waitcnt vmcnt(5)" ::: "memory")
#define VM0 asm volatile("s_waitcnt vmcnt(0)" ::: "memory")

#define PHASE(q, b, STAGE_STMT, VMSTMT) do {                                   \
    short8 a00 = ldA(b, 2*(q),     0);                                         \
    short8 a01 = ldA(b, 2*(q),     1);                                         \
    short8 a10 = ldA(b, 2*(q) + 1, 0);                                         \
    short8 a11 = ldA(b, 2*(q) + 1, 1);                                         \
    if ((q) == 0) {                                                            \
      bf00 = ldB(b, 0, 0); bf01 = ldB(b, 0, 1);                                \
      bf10 = ldB(b, 1, 0); bf11 = ldB(b, 1, 1);                                \
      bf20 = ldB(b, 2, 0); bf21 = ldB(b, 2, 1);                                \
      bf30 = ldB(b, 3, 0); bf31 = ldB(b, 3, 1);                                \
    }                                                                          \
    STAGE_STMT;                                                                \
    __builtin_amdgcn_sched_barrier(0);                                         \
    VMSTMT;                                                                    \
    __builtin_amdgcn_s_barrier();                                              \
    asm volatile("s_waitcnt lgkmcnt(0)" ::: "memory");                         \
    __builtin_amdgcn_sched_barrier(0);                                         \
    __builtin_amdgcn_s_setprio(1);                                             \
    MFMA_(acc[2*(q)  ][0], a00, bf00);                                         \
    MFMA_(acc[2*(q)  ][1], a00, bf10);                                         \
    MFMA_(acc[2*(q)  ][2], a00, bf20);                                         \
    MFMA_(acc[2*(q)  ][3], a00, bf30);                                         \
    MFMA_(acc[2*(q)+1][0], a10, bf00);                                         \
    MFMA_(acc[2*(q)+1][1], a10, bf10);                                         \
    MFMA_(acc[2*(q)+1][2], a10, bf20);                                         \
    MFMA_(acc[2*(q)+1][3], a10, bf30);                                         \
    MFMA_(acc[2*(q)  ][0], a01, bf01);                                         \
    MFMA_(acc[2*(q)  ][1], a01, bf11);                                         \
    MFMA_(acc[2*(q)  ][2], a01, bf21);                                         \
    MFMA_(acc[2*(q)  ][3], a01, bf31);                                         \
    MFMA_(acc[2*(q)+1][0], a11, bf01);                                         \
    MFMA_(acc[2*(q)+1][1], a11, bf11);                                         \
    MFMA_(acc[2*(q)+1][2], a11, bf21);                                         \
    MFMA_(acc[2*(q)+1][3], a11, bf31);                                         \
    __builtin_amdgcn_s_setprio(0);                                             \
    __builtin_amdgcn_s_barrier();                                              \
  } while (0)

// BM=128 variant: per phase one mi (=q), 2 A-reads, 8 MFMA.
#define PHASE1(q, b, STAGE_STMT, VMSTMT) do {                                  \
    short8 a0 = ldA(b, (q), 0);                                                \
    short8 a1 = ldA(b, (q), 1);                                                \
    if ((q) == 0) {                                                            \
      bf00 = ldB(b, 0, 0); bf01 = ldB(b, 0, 1);                                \
      bf10 = ldB(b, 1, 0); bf11 = ldB(b, 1, 1);                                \
      bf20 = ldB(b, 2, 0); bf21 = ldB(b, 2, 1);                                \
      bf30 = ldB(b, 3, 0); bf31 = ldB(b, 3, 1);                                \
    }                                                                          \
    STAGE_STMT;                                                                \
    __builtin_amdgcn_sched_barrier(0);                                         \
    VMSTMT;                                                                    \
    __builtin_amdgcn_s_barrier();                                              \
    asm volatile("s_waitcnt lgkmcnt(0)" ::: "memory");                         \
    __builtin_amdgcn_sched_barrier(0);                                         \
    __builtin_amdgcn_s_setprio(1);                                             \
    MFMA_(acc[(q)][0], a0, bf00);                                              \
    MFMA_(acc[(q)][1], a0, bf10);                                              \
    MFMA_(acc[(q)][2], a0, bf20);                                              \
    MFMA_(acc[(q)][3], a0, bf30);                                              \
    MFMA_(acc[(q)][0], a1, bf01);                                              \
    MFMA_(acc[(q)][1], a1, bf11);                                              \
    MFMA_(acc[(q)][2], a1, bf21);                                              \
    MFMA_(acc[(q)][3], a1, bf31);                                              \
    __builtin_amdgcn_s_setprio(0);                                             \
    __builtin_amdgcn_s_barrier();                                              \
  } while (0)

// Common body for BM=256 (gemm2), as in round 5 (verified).
#define GEMM_8PH_BODY(ASRC, BSRC)                                              \
  const int tid  = threadIdx.x;                                                \
  const int lane = tid & 63;                                                   \
  const int wave = tid >> 6;                                                   \
  const int wm   = wave >> 2;                                                  \
  const int wn   = wave & 3;                                                   \
  const int li8 = lane >> 3;                                                   \
  const int lc  = (lane & 7) ^ li8;                                            \
  const size_t stSrc = (size_t)li8 * ND + lc * 8;                              \
  const int stDst = lane * 8;                                                  \
  const u16* aSrc = (ASRC) + stSrc;                                            \
  const u16* bSrc = (BSRC) + stSrc;                                            \
  const int fr  = lane & 15;                                                   \
  const int rg  = lane >> 4;                                                   \
  const int ca0 = (((lane >> 4)    ) ^ (lane & 7)) * 8;                        \
  const int ca1 = (((lane >> 4) + 4) ^ (lane & 7)) * 8;                        \
  const int aOff = (wm * 128 + fr) * 64;                                       \
  const int bOff = 16384 + (wn * 64 + fr) * 64;                                \
  auto stageA = [&](int h, int t, int b) {                                     \
    _Pragma("unroll")                                                          \
    for (int jj = 0; jj < 2; ++jj) {                                           \
      int j = 2 * wave + jj;                                                   \
      int R = ((j >> 3) << 7) + h * 64 + ((j & 7) << 3);                       \
      gload16(aSrc + (size_t)R * ND + t * 64, lds + b * 32768 + R * 64 + stDst); \
    }                                                                          \
  };                                                                           \
  auto stageB = [&](int h, int t, int b) {                                     \
    _Pragma("unroll")                                                          \
    for (int jj = 0; jj < 2; ++jj) {                                           \
      int j = 2 * wave + jj;                                                   \
      int R = h * 128 + j * 8;                                                 \
      gload16(bSrc + (size_t)R * ND + t * 64, lds + b * 32768 + 16384 + R * 64 + stDst); \
    }                                                                          \
  };                                                                           \
  auto ldA = [&](int b, int mi, int kk) -> short8 {                            \
    return *(const short8*)(lds + b * 32768 + aOff + mi * 1024 + (kk ? ca1 : ca0)); \
  };                                                                           \
  auto ldB = [&](int b, int ni, int kk) -> short8 {                            \
    return *(const short8*)(lds + b * 32768 + bOff + ni * 1024 + (kk ? ca1 : ca0)); \
  };                                                                           \
  f32x4 acc[8][4];                                                             \
  f32x4 z = {0.f, 0.f, 0.f, 0.f};                                              \
  _Pragma("unroll")                                                            \
  for (int i = 0; i < 8; ++i)                                                  \
    _Pragma("unroll")                                                          \
    for (int j = 0; j < 4; ++j) acc[i][j] = z;                                 \
  short8 bf00, bf01, bf10, bf11, bf20, bf21, bf30, bf31;                       \
  stageA(0, 0, 0); stageA(1, 0, 0);                                            \
  stageB(0, 0, 0); stageB(1, 0, 0);                                            \
  stageB(0, 1, 1); stageB(1, 1, 1);                                            \
  stageA(0, 1, 1);                                                             \
  asm volatile("s_waitcnt vmcnt(6)" ::: "memory");                             \
  __builtin_amdgcn_s_barrier();                                                \
  _Pragma("unroll 1")                                                          \
  for (int it = 0; it < 7; ++it) {                                             \
    const int T = 2 * it;                                                      \
    PHASE(0, 0, stageA(1, T + 1, 1), NOVM);                                    \
    PHASE(1, 0, stageB(0, T + 2, 0), NOVM);                                    \
    PHASE(2, 0, stageB(1, T + 2, 0), NOVM);                                    \
    PHASE(3, 0, stageA(0, T + 2, 0), VM6);                                     \
    PHASE(0, 1, stageA(1, T + 2, 0), NOVM);                                    \
    PHASE(1, 1, stageB(0, T + 3, 1), NOVM);                                    \
    PHASE(2, 1, stageB(1, T + 3, 1), NOVM);                                    \
    PHASE(3, 1, stageA(0, T + 3, 1), VM6);                                     \
  }                                                                            \
  PHASE(0, 0, stageA(1, 15, 1), NOVM);                                         \
  PHASE(1, 0, NOVM, NOVM);                                                     \
  PHASE(2, 0, NOVM, NOVM);                                                     \
  PHASE(3, 0, NOVM, VM0);                                                      \
  PHASE(0, 1, NOVM, NOVM);                                                     \
  PHASE(1, 1, NOVM, NOVM);                                                     \
  PHASE(2, 1, NOVM, NOVM);                                                     \
  PHASE(3, 1, NOVM, NOVM);

// ---------------------------------------------------------------------------
// Kernel 4: gemm1_8ph — BM=128, BN=256 8-phase. Per head h:
// M[h][o][s] = sum_d A[h,o,d] * Wt[h,s,d].  Grid (4 n, 8 m, 8 h) = 256 blocks.
// LDS 96 KiB: per buf [A 128x64 (8192 u16) | B 256x64 (16384 u16)].
// vmcnt: A-half = 1 load/wave, B-half = 2 -> prologue/in-loop vmcnt(5).
// ---------------------------------------------------------------------------
__global__ __launch_bounds__(512, 2) void gemm1_8ph(const u16* __restrict__ Afac,
                                                    const u16* __restrict__ Wt,
                                                    u16* __restrict__ Mmat) {
  __shared__ __align__(16) u16 lds[49152];
  const int h  = blockIdx.z;
  const int m0 = blockIdx.y * 128;
  const int n0 = blockIdx.x * 256;
  const int tid  = threadIdx.x;
  const int lane = tid & 63;
  const int wave = tid >> 6;
  const int wm   = wave >> 2;
  const int wn   = wave & 3;
  const int li8 = lane >> 3;
  const int lc  = (lane & 7) ^ li8;
  const size_t stSrc = (size_t)li8 * ND + lc * 8;
  const int stDst = lane * 8;
  const u16* aSrc = Afac + ((size_t)h * ND + m0) * ND + stSrc;
  const u16* bSrc = Wt + ((size_t)h * ND + n0) * ND + stSrc;
  const int fr  = lane & 15;
  const int rg  = lane >> 4;
  const int ca0 = (((lane >> 4)    ) ^ (lane & 7)) * 8;
  const int ca1 = (((lane >> 4) + 4) ^ (lane & 7)) * 8;
  const int aOff = (wm * 64 + fr) * 64;
  const int bOff = 8192 + (wn * 64 + fr) * 64;

  // A interleaved halves: h2=0 -> rows {0-31, 64-95} (phase 0,1 rows);
  // h2=1 -> rows {32-63, 96-127} (phase 2,3 rows). 1 gload16 per wave.
  auto stageA = [&](int h2, int t, int b) {
    int R = (wave >> 2) * 64 + h2 * 32 + (wave & 3) * 8;
    gload16(aSrc + (size_t)R * ND + t * 64, lds + b * 24576 + R * 64 + stDst);
  };
  auto stageB = [&](int h2, int t, int b) {
#pragma unroll
    for (int jj = 0; jj < 2; ++jj) {
      int j = 2 * wave + jj;
      int R = h2 * 128 + j * 8;
      gload16(bSrc + (size_t)R * ND + t * 64, lds + b * 24576 + 8192 + R * 64 + stDst);
    }
  };
  auto ldA = [&](int b, int mi, int kk) -> short8 {
    return *(const short8*)(lds + b * 24576 + aOff + mi * 1024 + (kk ? ca1 : ca0));
  };
  auto ldB = [&](int b, int ni, int kk) -> short8 {
    return *(const short8*)(lds + b * 24576 + bOff + ni * 1024 + (kk ? ca1 : ca0));
  };

  f32x4 acc[4][4];
  f32x4 z = {0.f, 0.f, 0.f, 0.f};
#pragma unroll
  for (int i = 0; i < 4; ++i)
#pragma unroll
    for (int j = 0; j < 4; ++j) acc[i][j] = z;
  short8 bf00, bf01, bf10, bf11, bf20, bf21, bf30, bf31;

  // Prologue: tile0 (A0,A1,B0,B1 = 6 loads/wave) + 3 halves of tile1 (5 loads)
  stageA(0, 0, 0); stageA(1, 0, 0);
  stageB(0, 0, 0); stageB(1, 0, 0);
  stageB(0, 1, 1); stageB(1, 1, 1);
  stageA(0, 1, 1);
  VM5;
  __builtin_amdgcn_s_barrier();

#pragma unroll 1
  for (int it = 0; it < 7; ++it) {
    const int T = 2 * it;
    PHASE1(0, 0, stageA(1, T + 1, 1), NOVM);
    PHASE1(1, 0, stageB(0, T + 2, 0), NOVM);
    PHASE1(2, 0, stageB(1, T + 2, 0), NOVM);
    PHASE1(3, 0, stageA(0, T + 2, 0), VM5);
    PHASE1(0, 1, stageA(1, T + 2, 0), NOVM);
    PHASE1(1, 1, stageB(0, T + 3, 1), NOVM);
    PHASE1(2, 1, stageB(1, T + 3, 1), NOVM);
    PHASE1(3, 1, stageA(0, T + 3, 1), VM5);
  }
  PHASE1(0, 0, stageA(1, 15, 1), NOVM);
  PHASE1(1, 0, NOVM, NOVM);
  PHASE1(2, 0, NOVM, NOVM);
  PHASE1(3, 0, NOVM, VM0);
  PHASE1(0, 1, NOVM, NOVM);
  PHASE1(1, 1, NOVM, NOVM);
  PHASE1(2, 1, NOVM, NOVM);
  PHASE1(3, 1, NOVM, NOVM);

  // Epilogue: direct bf16 stores.
  u16* Mh = Mmat + (size_t)h * ND * ND;
  const int r0 = m0 + wm * 64 + rg * 4;
  const int c0 = n0 + wn * 64 + fr;
#pragma unroll
  for (int mi = 0; mi < 4; ++mi) {
#pragma unroll
    for (int r = 0; r < 4; ++r) {
      u16* orow = Mh + (size_t)(r0 + mi * 16 + r) * ND + c0;
#pragma unroll
      for (int ni = 0; ni < 4; ++ni)
        orow[ni * 16] = f2bf(acc[mi][ni][r]);
    }
  }
}

// ---------------------------------------------------------------------------
// Kernel 5: gemm2_8ph (round-2/5 proven config, untouched).
// ---------------------------------------------------------------------------
__global__ __launch_bounds__(512, 2) void gemm2_8ph(const u16* __restrict__ Xb,
                                                    const u16* __restrict__ Bm,
                                                    const float* __restrict__ Kc,
                                                    float* __restrict__ Out) {
  __shared__ __align__(16) u16 lds[65536];
  const int bid = blockIdx.x;
  const int swz = (bid & 7) * 64 + (bid >> 3);
  const int m0  = (swz >> 5) * 256;
  const int n0  = (swz & 31) * 256;
  GEMM_8PH_BODY(Xb + (size_t)m0 * ND, Bm + (size_t)n0 * ND)

  const int hH = n0 >> 10;
  const int r0 = m0 + wm * 128 + rg * 4;
  const int c0 = n0 + wn * 64 + fr;
  const int o0 = c0 & 1023;
  float bias[4];
#pragma unroll
  for (int ni = 0; ni < 4; ++ni) bias[ni] = Kc[c0 + ni * 16];
#pragma unroll
  for (int mi = 0; mi < 8; ++mi) {
#pragma unroll
    for (int r = 0; r < 4; ++r) {
      int rb = r0 + mi * 16 + r;              // global x row = b*512 + e
      float* orow = Out + ((size_t)(rb >> 9) * 4096 + hH * 512 + (rb & 511)) * 1024 + o0;
#pragma unroll
      for (int ni = 0; ni < 4; ++ni)
        orow[ni * 16] = acc[mi][ni][r] + bias[ni];
    }
  }
}

// ---------------------------------------------------------------------------
extern "C" void kernel_launch(void* const* d_in, const int* in_sizes, int n_in,
                              void* d_out, int out_size, void* d_ws, size_t ws_size,
                              hipStream_t stream) {
  (void)in_sizes; (void)n_in; (void)out_size; (void)ws_size;
  const float* x      = (const float*)d_in[0];
  const float* proj_w = (const float*)d_in[1];
  const float* proj_b = (const float*)d_in[2];
  const float* mix_w  = (const float*)d_in[3];
  const float* mix_b  = (const float*)d_in[4];
  const float* out_w  = (const float*)d_in[5];
  const float* out_b  = (const float*)d_in[6];
  float* Out = (float*)d_out;

  // Scratch carved from d_out (dead before gemm2 writes Out): Wt, Afac
  u16* Wt   = (u16*)d_out;
  u16* Afac = (u16*)d_out + (size_t)8 * 1024 * 1024;
  // Scratch in d_ws: Xb (8 MiB) + Mmat (16 MiB) + Kc (32 KiB)
  u16*   Xb   = (u16*)d_ws;
  u16*   Mmat = (u16*)((char*)d_ws + ((size_t)8 << 20));
  float* Kc   = (float*)((char*)d_ws + ((size_t)24 << 20));

  convert_x_kernel<<<4096, 256, 0, stream>>>(x, Xb);
  transpose_w_kernel<<<dim3(16, 16, NH), 256, 0, stream>>>(proj_w, Wt);
  scan2_kernel<<<ND, 256, 0, stream>>>(out_w, mix_w, mix_b, proj_b, out_b, Afac, Kc);
  gemm1_8ph<<<dim3(4, 8, NH), 512, 0, stream>>>(Afac, Wt, Mmat);
  gemm2_8ph<<<512, 512, 0, stream>>>(Xb, Mmat, Kc, Out);
}

// Round 7
// 114.596 us; speedup vs baseline: 1.3093x; 1.1188x over previous
//
#include <hip/hip_runtime.h>

// Problem constants (S == DIM == HID == 1024)
#define NH    8      // heads
#define NE    512    // experts per head-group (E)
#define NB    8      // batch
#define ND    1024   // DIM == HID == S
#define NROW  4096   // NB * NE  (rows of x)

typedef unsigned short u16;
typedef __attribute__((ext_vector_type(8))) short short8;
typedef __attribute__((ext_vector_type(4))) float f32x4;

__device__ __forceinline__ u16 f2bf(float f) {
  unsigned int u = __float_as_uint(f);
  u += 0x7fffu + ((u >> 16) & 1u);   // round-to-nearest-even
  return (u16)(u >> 16);
}

__device__ __forceinline__ void gload16(const u16* g, u16* l) {
  __builtin_amdgcn_global_load_lds(
      (const __attribute__((address_space(1))) unsigned int*)(const void*)g,
      (__attribute__((address_space(3))) unsigned int*)(void*)l, 16, 0, 0);
}

// ---------------------------------------------------------------------------
// Fused pre-kernel: scan2 (blocks [0,1024)) | transpose_w ([1024,3072)) |
// convert_x ([3072,7168)). All three are independent; fusing removes two
// launch gaps and lets them share HBM BW.
// ---------------------------------------------------------------------------
__global__ __launch_bounds__(256) void fused_pre_kernel(
    const float* __restrict__ X, u16* __restrict__ Xb,
    const float* __restrict__ W, u16* __restrict__ Wt,
    const float* __restrict__ out_w, const float* __restrict__ mix_w,
    const float* __restrict__ mix_b, const float* __restrict__ proj_b,
    const float* __restrict__ out_b,
    u16* __restrict__ Afac, float* __restrict__ Kc) {
  __shared__ float tile[64][65];   // transpose branch
  __shared__ float wsum[4];        // scan branch
  __shared__ float red[4];
  const int bz = blockIdx.x;
  const int t  = threadIdx.x;

  if (bz < 1024) {
    // ---- scan2: one block per o; loop h; out_w row read once ----
    const int o = bz;
    const int lane = t & 63, wave = t >> 6;
    float ow[4];
#pragma unroll
    for (int k = 0; k < 4; ++k) ow[k] = out_w[(size_t)o * ND + 1023 - (4 * t + k)];
    float ob = out_b[o];
#pragma unroll 1
    for (int h = 0; h < NH; ++h) {
      const float* mwr = mix_w + (size_t)h * ND;
      const float* mbr = mix_b + (size_t)h * ND;
      const float* pbr = proj_b + (size_t)h * ND;
      float l[4];
      float run = 0.f, mbdot = 0.f;
#pragma unroll
      for (int k = 0; k < 4; ++k) {
        int j = 1023 - (4 * t + k);        // reversed order
        mbdot += ow[k] * mbr[j];
        run += ow[k] * mwr[j];
        l[k] = run;
      }
      float tsum = run;
      float sc = tsum;
#pragma unroll
      for (int d = 1; d < 64; d <<= 1) {
        float other = __shfl_up(sc, d);
        if (lane >= d) sc += other;
      }
      if (lane == 63) wsum[wave] = sc;
      __syncthreads();
      float wprefix = 0.f;
      for (int w = 0; w < wave; ++w) wprefix += wsum[w];
      float excl = wprefix + sc - tsum;

      float cdot = 0.f;
      ushort4 pack;
      u16* pk = (u16*)&pack;
#pragma unroll
      for (int k = 0; k < 4; ++k) {
        int d = 1023 - (4 * t + k);
        float a = excl + l[k];
        cdot += a * pbr[d];
        pk[3 - k] = f2bf(a);
      }
      *(ushort4*)(Afac + ((size_t)(h * ND + o)) * ND + (1020 - 4 * t)) = pack;

      float tot = cdot + mbdot;
#pragma unroll
      for (int m = 32; m >= 1; m >>= 1) tot += __shfl_xor(tot, m);
      if (lane == 0) red[wave] = tot;
      __syncthreads();
      if (t == 0) Kc[h * ND + o] = red[0] + red[1] + red[2] + red[3] + ob;
    }
  } else if (bz < 3072) {
    // ---- transpose_w: Wt[h][s][d] = bf16(W[h][d][s]) ----
    const int f  = bz - 1024;
    const int h  = f >> 8;
    const int d0 = ((f >> 4) & 15) * 64;
    const int s0 = (f & 15) * 64;
    const int tr = t >> 4;
    const int tc = t & 15;
#pragma unroll
    for (int i = 0; i < 4; ++i) {
      int d = tr + i * 16;
      float4 v = *(const float4*)(W + ((size_t)h * ND + d0 + d) * ND + s0 + tc * 4);
      tile[d][tc * 4 + 0] = v.x;
      tile[d][tc * 4 + 1] = v.y;
      tile[d][tc * 4 + 2] = v.z;
      tile[d][tc * 4 + 3] = v.w;
    }
    __syncthreads();
#pragma unroll
    for (int i = 0; i < 4; ++i) {
      int s  = tr + i * 16;
      int dd = tc * 4;
      ushort4 o;
      o.x = f2bf(tile[dd + 0][s]);
      o.y = f2bf(tile[dd + 1][s]);
      o.z = f2bf(tile[dd + 2][s]);
      o.w = f2bf(tile[dd + 3][s]);
      *(ushort4*)(Wt + ((size_t)h * ND + s0 + s) * ND + d0 + dd) = o;
    }
  } else {
    // ---- convert_x: f32 -> bf16, float4 granularity ----
    int i = (bz - 3072) * 256 + t;
    float4 v = ((const float4*)X)[i];
    ushort4 o;
    o.x = f2bf(v.x); o.y = f2bf(v.y); o.z = f2bf(v.z); o.w = f2bf(v.w);
    ((ushort4*)Xb)[i] = o;
  }
}

// ---------------------------------------------------------------------------
// Shared defs for 8-phase cores
// ---------------------------------------------------------------------------
#define MFMA_(d, a, b) d = __builtin_amdgcn_mfma_f32_16x16x32_bf16(a, b, d, 0, 0, 0)
#define NOVM ((void)0)
#define VM6 asm volatile("s_waitcnt vmcnt(6)" ::: "memory")
#define VM5 asm volatile("s_waitcnt vmcnt(5)" ::: "memory")
#define VM0 asm volatile("s_waitcnt vmcnt(0)" ::: "memory")

#define PHASE(q, b, STAGE_STMT, VMSTMT) do {                                   \
    short8 a00 = ldA(b, 2*(q),     0);                                         \
    short8 a01 = ldA(b, 2*(q),     1);                                         \
    short8 a10 = ldA(b, 2*(q) + 1, 0);                                         \
    short8 a11 = ldA(b, 2*(q) + 1, 1);                                         \
    if ((q) == 0) {                                                            \
      bf00 = ldB(b, 0, 0); bf01 = ldB(b, 0, 1);                                \
      bf10 = ldB(b, 1, 0); bf11 = ldB(b, 1, 1);                                \
      bf20 = ldB(b, 2, 0); bf21 = ldB(b, 2, 1);                                \
      bf30 = ldB(b, 3, 0); bf31 = ldB(b, 3, 1);                                \
    }                                                                          \
    STAGE_STMT;                                                                \
    __builtin_amdgcn_sched_barrier(0);                                         \
    VMSTMT;                                                                    \
    __builtin_amdgcn_s_barrier();                                              \
    asm volatile("s_waitcnt lgkmcnt(0)" ::: "memory");                         \
    __builtin_amdgcn_sched_barrier(0);                                         \
    __builtin_amdgcn_s_setprio(1);                                             \
    MFMA_(acc[2*(q)  ][0], a00, bf00);                                         \
    MFMA_(acc[2*(q)  ][1], a00, bf10);                                         \
    MFMA_(acc[2*(q)  ][2], a00, bf20);                                         \
    MFMA_(acc[2*(q)  ][3], a00, bf30);                                         \
    MFMA_(acc[2*(q)+1][0], a10, bf00);                                         \
    MFMA_(acc[2*(q)+1][1], a10, bf10);                                         \
    MFMA_(acc[2*(q)+1][2], a10, bf20);                                         \
    MFMA_(acc[2*(q)+1][3], a10, bf30);                                         \
    MFMA_(acc[2*(q)  ][0], a01, bf01);                                         \
    MFMA_(acc[2*(q)  ][1], a01, bf11);                                         \
    MFMA_(acc[2*(q)  ][2], a01, bf21);                                         \
    MFMA_(acc[2*(q)  ][3], a01, bf31);                                         \
    MFMA_(acc[2*(q)+1][0], a11, bf01);                                         \
    MFMA_(acc[2*(q)+1][1], a11, bf11);                                         \
    MFMA_(acc[2*(q)+1][2], a11, bf21);                                         \
    MFMA_(acc[2*(q)+1][3], a11, bf31);                                         \
    __builtin_amdgcn_s_setprio(0);                                             \
    __builtin_amdgcn_s_barrier();                                              \
  } while (0)

// BM=128 variant: per phase one mi (=q), 2 A-reads, 8 MFMA.
#define PHASE1(q, b, STAGE_STMT, VMSTMT) do {                                  \
    short8 a0 = ldA(b, (q), 0);                                                \
    short8 a1 = ldA(b, (q), 1);                                                \
    if ((q) == 0) {                                                            \
      bf00 = ldB(b, 0, 0); bf01 = ldB(b, 0, 1);                                \
      bf10 = ldB(b, 1, 0); bf11 = ldB(b, 1, 1);                                \
      bf20 = ldB(b, 2, 0); bf21 = ldB(b, 2, 1);                                \
      bf30 = ldB(b, 3, 0); bf31 = ldB(b, 3, 1);                                \
    }                                                                          \
    STAGE_STMT;                                                                \
    __builtin_amdgcn_sched_barrier(0);                                         \
    VMSTMT;                                                                    \
    __builtin_amdgcn_s_barrier();                                              \
    asm volatile("s_waitcnt lgkmcnt(0)" ::: "memory");                         \
    __builtin_amdgcn_sched_barrier(0);                                         \
    __builtin_amdgcn_s_setprio(1);                                             \
    MFMA_(acc[(q)][0], a0, bf00);                                              \
    MFMA_(acc[(q)][1], a0, bf10);                                              \
    MFMA_(acc[(q)][2], a0, bf20);                                              \
    MFMA_(acc[(q)][3], a0, bf30);                                              \
    MFMA_(acc[(q)][0], a1, bf01);                                              \
    MFMA_(acc[(q)][1], a1, bf11);                                              \
    MFMA_(acc[(q)][2], a1, bf21);                                              \
    MFMA_(acc[(q)][3], a1, bf31);                                              \
    __builtin_amdgcn_s_setprio(0);                                             \
    __builtin_amdgcn_s_barrier();                                              \
  } while (0)

// Common body for BM=256 (gemm2), verified rounds 2/5/6.
#define GEMM_8PH_BODY(ASRC, BSRC)                                              \
  const int tid  = threadIdx.x;                                                \
  const int lane = tid & 63;                                                   \
  const int wave = tid >> 6;                                                   \
  const int wm   = wave >> 2;                                                  \
  const int wn   = wave & 3;                                                   \
  const int li8 = lane >> 3;                                                   \
  const int lc  = (lane & 7) ^ li8;                                            \
  const size_t stSrc = (size_t)li8 * ND + lc * 8;                              \
  const int stDst = lane * 8;                                                  \
  const u16* aSrc = (ASRC) + stSrc;                                            \
  const u16* bSrc = (BSRC) + stSrc;                                            \
  const int fr  = lane & 15;                                                   \
  const int rg  = lane >> 4;                                                   \
  const int ca0 = (((lane >> 4)    ) ^ (lane & 7)) * 8;                        \
  const int ca1 = (((lane >> 4) + 4) ^ (lane & 7)) * 8;                        \
  const int aOff = (wm * 128 + fr) * 64;                                       \
  const int bOff = 16384 + (wn * 64 + fr) * 64;                                \
  auto stageA = [&](int h, int t, int b) {                                     \
    _Pragma("unroll")                                                          \
    for (int jj = 0; jj < 2; ++jj) {                                           \
      int j = 2 * wave + jj;                                                   \
      int R = ((j >> 3) << 7) + h * 64 + ((j & 7) << 3);                       \
      gload16(aSrc + (size_t)R * ND + t * 64, lds + b * 32768 + R * 64 + stDst); \
    }                                                                          \
  };                                                                           \
  auto stageB = [&](int h, int t, int b) {                                     \
    _Pragma("unroll")                                                          \
    for (int jj = 0; jj < 2; ++jj) {                                           \
      int j = 2 * wave + jj;                                                   \
      int R = h * 128 + j * 8;                                                 \
      gload16(bSrc + (size_t)R * ND + t * 64, lds + b * 32768 + 16384 + R * 64 + stDst); \
    }                                                                          \
  };                                                                           \
  auto ldA = [&](int b, int mi, int kk) -> short8 {                            \
    return *(const short8*)(lds + b * 32768 + aOff + mi * 1024 + (kk ? ca1 : ca0)); \
  };                                                                           \
  auto ldB = [&](int b, int ni, int kk) -> short8 {                            \
    return *(const short8*)(lds + b * 32768 + bOff + ni * 1024 + (kk ? ca1 : ca0)); \
  };                                                                           \
  f32x4 acc[8][4];                                                             \
  f32x4 z = {0.f, 0.f, 0.f, 0.f};                                              \
  _Pragma("unroll")                                                            \
  for (int i = 0; i < 8; ++i)                                                  \
    _Pragma("unroll")                                                          \
    for (int j = 0; j < 4; ++j) acc[i][j] = z;                                 \
  short8 bf00, bf01, bf10, bf11, bf20, bf21, bf30, bf31;                       \
  stageA(0, 0, 0); stageA(1, 0, 0);                                            \
  stageB(0, 0, 0); stageB(1, 0, 0);                                            \
  stageB(0, 1, 1); stageB(1, 1, 1);                                            \
  stageA(0, 1, 1);                                                             \
  asm volatile("s_waitcnt vmcnt(6)" ::: "memory");                             \
  __builtin_amdgcn_s_barrier();                                                \
  _Pragma("unroll 1")                                                          \
  for (int it = 0; it < 7; ++it) {                                             \
    const int T = 2 * it;                                                      \
    PHASE(0, 0, stageA(1, T + 1, 1), NOVM);                                    \
    PHASE(1, 0, stageB(0, T + 2, 0), NOVM);                                    \
    PHASE(2, 0, stageB(1, T + 2, 0), NOVM);                                    \
    PHASE(3, 0, stageA(0, T + 2, 0), VM6);                                     \
    PHASE(0, 1, stageA(1, T + 2, 0), NOVM);                                    \
    PHASE(1, 1, stageB(0, T + 3, 1), NOVM);                                    \
    PHASE(2, 1, stageB(1, T + 3, 1), NOVM);                                    \
    PHASE(3, 1, stageA(0, T + 3, 1), VM6);                                     \
  }                                                                            \
  PHASE(0, 0, stageA(1, 15, 1), NOVM);                                         \
  PHASE(1, 0, NOVM, NOVM);                                                     \
  PHASE(2, 0, NOVM, NOVM);                                                     \
  PHASE(3, 0, NOVM, VM0);                                                      \
  PHASE(0, 1, NOVM, NOVM);                                                     \
  PHASE(1, 1, NOVM, NOVM);                                                     \
  PHASE(2, 1, NOVM, NOVM);                                                     \
  PHASE(3, 1, NOVM, NOVM);

// ---------------------------------------------------------------------------
// Kernel 4: gemm1_8ph — BM=128, BN=256 8-phase (round-6 verified, unchanged).
// ---------------------------------------------------------------------------
__global__ __launch_bounds__(512, 2) void gemm1_8ph(const u16* __restrict__ Afac,
                                                    const u16* __restrict__ Wt,
                                                    u16* __restrict__ Mmat) {
  __shared__ __align__(16) u16 lds[49152];
  const int h  = blockIdx.z;
  const int m0 = blockIdx.y * 128;
  const int n0 = blockIdx.x * 256;
  const int tid  = threadIdx.x;
  const int lane = tid & 63;
  const int wave = tid >> 6;
  const int wm   = wave >> 2;
  const int wn   = wave & 3;
  const int li8 = lane >> 3;
  const int lc  = (lane & 7) ^ li8;
  const size_t stSrc = (size_t)li8 * ND + lc * 8;
  const int stDst = lane * 8;
  const u16* aSrc = Afac + ((size_t)h * ND + m0) * ND + stSrc;
  const u16* bSrc = Wt + ((size_t)h * ND + n0) * ND + stSrc;
  const int fr  = lane & 15;
  const int rg  = lane >> 4;
  const int ca0 = (((lane >> 4)    ) ^ (lane & 7)) * 8;
  const int ca1 = (((lane >> 4) + 4) ^ (lane & 7)) * 8;
  const int aOff = (wm * 64 + fr) * 64;
  const int bOff = 8192 + (wn * 64 + fr) * 64;

  auto stageA = [&](int h2, int t, int b) {
    int R = (wave >> 2) * 64 + h2 * 32 + (wave & 3) * 8;
    gload16(aSrc + (size_t)R * ND + t * 64, lds + b * 24576 + R * 64 + stDst);
  };
  auto stageB = [&](int h2, int t, int b) {
#pragma unroll
    for (int jj = 0; jj < 2; ++jj) {
      int j = 2 * wave + jj;
      int R = h2 * 128 + j * 8;
      gload16(bSrc + (size_t)R * ND + t * 64, lds + b * 24576 + 8192 + R * 64 + stDst);
    }
  };
  auto ldA = [&](int b, int mi, int kk) -> short8 {
    return *(const short8*)(lds + b * 24576 + aOff + mi * 1024 + (kk ? ca1 : ca0));
  };
  auto ldB = [&](int b, int ni, int kk) -> short8 {
    return *(const short8*)(lds + b * 24576 + bOff + ni * 1024 + (kk ? ca1 : ca0));
  };

  f32x4 acc[4][4];
  f32x4 z = {0.f, 0.f, 0.f, 0.f};
#pragma unroll
  for (int i = 0; i < 4; ++i)
#pragma unroll
    for (int j = 0; j < 4; ++j) acc[i][j] = z;
  short8 bf00, bf01, bf10, bf11, bf20, bf21, bf30, bf31;

  stageA(0, 0, 0); stageA(1, 0, 0);
  stageB(0, 0, 0); stageB(1, 0, 0);
  stageB(0, 1, 1); stageB(1, 1, 1);
  stageA(0, 1, 1);
  VM5;
  __builtin_amdgcn_s_barrier();

#pragma unroll 1
  for (int it = 0; it < 7; ++it) {
    const int T = 2 * it;
    PHASE1(0, 0, stageA(1, T + 1, 1), NOVM);
    PHASE1(1, 0, stageB(0, T + 2, 0), NOVM);
    PHASE1(2, 0, stageB(1, T + 2, 0), NOVM);
    PHASE1(3, 0, stageA(0, T + 2, 0), VM5);
    PHASE1(0, 1, stageA(1, T + 2, 0), NOVM);
    PHASE1(1, 1, stageB(0, T + 3, 1), NOVM);
    PHASE1(2, 1, stageB(1, T + 3, 1), NOVM);
    PHASE1(3, 1, stageA(0, T + 3, 1), VM5);
  }
  PHASE1(0, 0, stageA(1, 15, 1), NOVM);
  PHASE1(1, 0, NOVM, NOVM);
  PHASE1(2, 0, NOVM, NOVM);
  PHASE1(3, 0, NOVM, VM0);
  PHASE1(0, 1, NOVM, NOVM);
  PHASE1(1, 1, NOVM, NOVM);
  PHASE1(2, 1, NOVM, NOVM);
  PHASE1(3, 1, NOVM, NOVM);

  u16* Mh = Mmat + (size_t)h * ND * ND;
  const int r0 = m0 + wm * 64 + rg * 4;
  const int c0 = n0 + wn * 64 + fr;
#pragma unroll
  for (int mi = 0; mi < 4; ++mi) {
#pragma unroll
    for (int r = 0; r < 4; ++r) {
      u16* orow = Mh + (size_t)(r0 + mi * 16 + r) * ND + c0;
#pragma unroll
      for (int ni = 0; ni < 4; ++ni)
        orow[ni * 16] = f2bf(acc[mi][ni][r]);
    }
  }
}

// ---------------------------------------------------------------------------
// Kernel 5: gemm2_8ph — core/epilogue unchanged; RECT XCD swizzle:
// each XCD (bid&7) owns an 8m x 8n rectangle of the 16x32 tile grid.
// Round 1 (bid<256) per XCD = 4m x 8n -> working set ~6 MB (~L2-resident).
// ---------------------------------------------------------------------------
__global__ __launch_bounds__(512, 2) void gemm2_8ph(const u16* __restrict__ Xb,
                                                    const u16* __restrict__ Bm,
                                                    const float* __restrict__ Kc,
                                                    float* __restrict__ Out) {
  __shared__ __align__(16) u16 lds[65536];
  const int bid = blockIdx.x;
  const int xcd = bid & 7;
  const int loc = bid >> 3;                         // [0,64)
  const int m0  = (((xcd >> 2) << 3) + (loc >> 3)) * 256;   // 16 m-blocks
  const int n0  = (((xcd & 3) << 3) + (loc & 7)) * 256;     // 32 n-blocks
  GEMM_8PH_BODY(Xb + (size_t)m0 * ND, Bm + (size_t)n0 * ND)

  const int hH = n0 >> 10;
  const int r0 = m0 + wm * 128 + rg * 4;
  const int c0 = n0 + wn * 64 + fr;
  const int o0 = c0 & 1023;
  float bias[4];
#pragma unroll
  for (int ni = 0; ni < 4; ++ni) bias[ni] = Kc[c0 + ni * 16];
#pragma unroll
  for (int mi = 0; mi < 8; ++mi) {
#pragma unroll
    for (int r = 0; r < 4; ++r) {
      int rb = r0 + mi * 16 + r;              // global x row = b*512 + e
      float* orow = Out + ((size_t)(rb >> 9) * 4096 + hH * 512 + (rb & 511)) * 1024 + o0;
#pragma unroll
      for (int ni = 0; ni < 4; ++ni)
        orow[ni * 16] = acc[mi][ni][r] + bias[ni];
    }
  }
}

// ---------------------------------------------------------------------------
extern "C" void kernel_launch(void* const* d_in, const int* in_sizes, int n_in,
                              void* d_out, int out_size, void* d_ws, size_t ws_size,
                              hipStream_t stream) {
  (void)in_sizes; (void)n_in; (void)out_size; (void)ws_size;
  const float* x      = (const float*)d_in[0];
  const float* proj_w = (const float*)d_in[1];
  const float* proj_b = (const float*)d_in[2];
  const float* mix_w  = (const float*)d_in[3];
  const float* mix_b  = (const float*)d_in[4];
  const float* out_w  = (const float*)d_in[5];
  const float* out_b  = (const float*)d_in[6];
  float* Out = (float*)d_out;

  // Scratch carved from d_out (dead before gemm2 writes Out): Wt, Afac
  u16* Wt   = (u16*)d_out;
  u16* Afac = (u16*)d_out + (size_t)8 * 1024 * 1024;
  // Scratch in d_ws: Xb (8 MiB) + Mmat (16 MiB) + Kc (32 KiB)
  u16*   Xb   = (u16*)d_ws;
  u16*   Mmat = (u16*)((char*)d_ws + ((size_t)8 << 20));
  float* Kc   = (float*)((char*)d_ws + ((size_t)24 << 20));

  fused_pre_kernel<<<7168, 256, 0, stream>>>(x, Xb, proj_w, Wt,
                                             out_w, mix_w, mix_b, proj_b, out_b,
                                             Afac, Kc);
  gemm1_8ph<<<dim3(4, 8, NH), 512, 0, stream>>>(Afac, Wt, Mmat);
  gemm2_8ph<<<512, 512, 0, stream>>>(Xb, Mmat, Kc, Out);
}